// Round 1
// baseline (305.566 us; speedup 1.0000x reference)
//
#include <hip/hip_runtime.h>
#include <hip/hip_fp16.h>

#define S_LEN 2048
#define NH 16
#define DK 64
#define DM 1024
#define NB 2

typedef _Float16 half8 __attribute__((ext_vector_type(8)));
typedef _Float16 half4v __attribute__((ext_vector_type(4)));
typedef float f32x4 __attribute__((ext_vector_type(4)));

// ---------------- conversion kernels ----------------

__global__ __launch_bounds__(256) void conv_f32_f16(const float* __restrict__ in,
                                                    _Float16* __restrict__ out, int n4) {
  int i = blockIdx.x * 256 + threadIdx.x;
  if (i >= n4) return;
  float4 v = ((const float4*)in)[i];
  half4v o;
  o[0] = (_Float16)v.x; o[1] = (_Float16)v.y; o[2] = (_Float16)v.z; o[3] = (_Float16)v.w;
  ((half4v*)out)[i] = o;
}

// Wt[n][k] = (f16)W[k][n], both 1024x1024
__global__ __launch_bounds__(256) void transpose_conv(const float* __restrict__ W,
                                                      _Float16* __restrict__ Wt) {
  __shared__ float tile[32][33];
  int tx = threadIdx.x, ty = threadIdx.y;
  int nx = blockIdx.x * 32 + tx;
  int ky = blockIdx.y * 32;
#pragma unroll
  for (int i = 0; i < 32; i += 8) tile[ty + i][tx] = W[(size_t)(ky + ty + i) * DM + nx];
  __syncthreads();
  int kx = ky + tx;
  int ny = blockIdx.x * 32;
#pragma unroll
  for (int i = 0; i < 32; i += 8)
    Wt[(size_t)(ny + ty + i) * DM + kx] = (_Float16)tile[tx][ty + i];
}

// tab[h][r] = table[bucket(r-2047)][h], r in [0,4095)
// exact: int(log(a/8)/log(16)*8) == ilog2(a*a) - 6 for a >= 8
__global__ __launch_bounds__(256) void bias_tab_kernel(const float* __restrict__ table,
                                                       float* __restrict__ tab) {
  int i = blockIdx.x * 256 + threadIdx.x;
  if (i >= NH * 4095) return;
  int h = i / 4095, r = i - h * 4095;
  int rel = r - 2047;              // rel = k - q
  int bucket = rel > 0 ? 16 : 0;
  int a = rel < 0 ? -rel : rel;
  if (a < 8) {
    bucket += a;
  } else {
    int lg = 31 - __clz(a * a);    // floor(2*log2(a))
    int large = 8 + (lg - 6);
    bucket += (large < 15 ? large : 15);
  }
  tab[i] = table[bucket * NH + h];
}

// ---------------- fp16 MFMA GEMM: C = A(MxK) @ Bt(NxK)^T ----------------
// MODE 0: scatter-store f16 into QKV buffers (B,H,S,D); MODE 1: f32 row-major out.
template <int MODE>
__global__ __launch_bounds__(256) void gemm_f16(const _Float16* __restrict__ A,
                                                const _Float16* __restrict__ Bt,
                                                void* __restrict__ Cout,
                                                int M, int N, int K) {
  __shared__ _Float16 As[128 * 40];  // [row][k], pad 32->40 elems
  __shared__ _Float16 Bs[128 * 40];  // [col(n)][k]
  int t = threadIdx.x;
  int m0 = blockIdx.y * 128, n0 = blockIdx.x * 128;
  int w = t >> 6, lane = t & 63, l15 = lane & 15, quad = lane >> 4;
  int wr = (w >> 1) * 64, wc = (w & 1) * 64;

  f32x4 acc[4][4];
#pragma unroll
  for (int i = 0; i < 4; i++)
#pragma unroll
    for (int j = 0; j < 4; j++) acc[i][j] = (f32x4){0.f, 0.f, 0.f, 0.f};

  int r0 = t >> 2, o0 = (t & 3) * 8;  // staging: 2 16B-chunks per thread
  int r1 = r0 + 64;

  for (int k0 = 0; k0 < K; k0 += 32) {
    __syncthreads();
    uint4 a0 = *(const uint4*)(A + (size_t)(m0 + r0) * K + k0 + o0);
    uint4 a1 = *(const uint4*)(A + (size_t)(m0 + r1) * K + k0 + o0);
    uint4 b0 = *(const uint4*)(Bt + (size_t)(n0 + r0) * K + k0 + o0);
    uint4 b1 = *(const uint4*)(Bt + (size_t)(n0 + r1) * K + k0 + o0);
    *(uint4*)(As + r0 * 40 + o0) = a0;
    *(uint4*)(As + r1 * 40 + o0) = a1;
    *(uint4*)(Bs + r0 * 40 + o0) = b0;
    *(uint4*)(Bs + r1 * 40 + o0) = b1;
    __syncthreads();
    half8 af[4], bf[4];
#pragma unroll
    for (int i = 0; i < 4; i++) af[i] = *(half8*)(As + (wr + i * 16 + l15) * 40 + quad * 8);
#pragma unroll
    for (int i = 0; i < 4; i++) bf[i] = *(half8*)(Bs + (wc + i * 16 + l15) * 40 + quad * 8);
#pragma unroll
    for (int i = 0; i < 4; i++)
#pragma unroll
      for (int j = 0; j < 4; j++)
        acc[i][j] = __builtin_amdgcn_mfma_f32_16x16x32_f16(af[i], bf[j], acc[i][j], 0, 0, 0);
  }

#pragma unroll
  for (int i = 0; i < 4; i++)
#pragma unroll
    for (int j = 0; j < 4; j++)
#pragma unroll
      for (int r = 0; r < 4; r++) {
        int row = m0 + wr + i * 16 + quad * 4 + r;   // C/D: row=(lane>>4)*4+reg
        int col = n0 + wc + j * 16 + l15;            //      col=lane&15
        float v = acc[i][j][r];
        if (MODE == 0) {
          int which = col >> 10, rem = col & 1023, h = rem >> 6, d = rem & 63;
          int b = row >> 11, s = row & 2047;
          _Float16* q = (_Float16*)Cout;
          q[(size_t)which * (NB * NH * S_LEN * DK) +
            (((size_t)(b * NH + h) * S_LEN + s) * DK + d)] = (_Float16)v;
        } else {
          ((float*)Cout)[(size_t)row * N + col] = v;
        }
      }
}

// ---------------- flash attention ----------------
// grid (S/64, H, B), block 256 = 4 waves; wave w owns q rows [q0+16w, q0+16w+16)
__global__ __launch_bounds__(256) void attn_kernel(const _Float16* __restrict__ Q,
                                                   const _Float16* __restrict__ K,
                                                   const _Float16* __restrict__ V,
                                                   const float* __restrict__ btab,
                                                   _Float16* __restrict__ attn_out) {
  __shared__ float slab[2112];          // bias slab for this (h, q-block)
  __shared__ _Float16 Vt[64 * 72];      // V^T chunk: [d][k], pad 64->72
  __shared__ _Float16 Ps[4][16 * 72];   // per-wave P tile in A-layout rows
  int t = threadIdx.x;
  int q0 = blockIdx.x * 64, h = blockIdx.y, b = blockIdx.z;
  int w = t >> 6, lane = t & 63, l15 = lane & 15, quad = lane >> 4;

  // stage bias slab: slab[i] = bias[h][(1984 - q0) + i]; lookup idx = k + 63 - (q - q0)
  const float* brow = btab + h * 4095 + (1984 - q0);
  for (int i = t; i < 2111; i += 256) slab[i] = brow[i];

  const _Float16* Qb = Q + (size_t)(b * NH + h) * S_LEN * DK;
  const _Float16* Kb = K + (size_t)(b * NH + h) * S_LEN * DK;
  const _Float16* Vb = V + (size_t)(b * NH + h) * S_LEN * DK;

  int qrb = w * 16;  // wave's q-row base within block
  int sQ = q0 + qrb + l15;
  half8 qf0 = *(const half8*)(Qb + (size_t)sQ * DK + quad * 8);
  half8 qf1 = *(const half8*)(Qb + (size_t)sQ * DK + 32 + quad * 8);

  f32x4 o[4];
#pragma unroll
  for (int i = 0; i < 4; i++) o[i] = (f32x4){0.f, 0.f, 0.f, 0.f};
  float mrow[4], lrow[4];
#pragma unroll
  for (int r = 0; r < 4; r++) { mrow[r] = -INFINITY; lrow[r] = 0.f; }

  int vk = t & 63, vd = (t >> 6) * 16;  // Vt staging assignment

  for (int k0 = 0; k0 < S_LEN; k0 += 64) {
    __syncthreads();
    // stage V^T chunk
    uint4 v0 = *(const uint4*)(Vb + (size_t)(k0 + vk) * DK + vd);
    uint4 v1 = *(const uint4*)(Vb + (size_t)(k0 + vk) * DK + vd + 8);
    const _Float16* e0 = (const _Float16*)&v0;
    const _Float16* e1 = (const _Float16*)&v1;
#pragma unroll
    for (int jj = 0; jj < 8; jj++) Vt[(vd + jj) * 72 + vk] = e0[jj];
#pragma unroll
    for (int jj = 0; jj < 8; jj++) Vt[(vd + 8 + jj) * 72 + vk] = e1[jj];
    __syncthreads();

    // scores: S[q][k] = Q.K^T + bias   (4 tiles of 16 k-cols)
    f32x4 st[4];
#pragma unroll
    for (int kt = 0; kt < 4; kt++) {
      int krow = k0 + kt * 16 + l15;
      half8 kf0 = *(const half8*)(Kb + (size_t)krow * DK + quad * 8);
      half8 kf1 = *(const half8*)(Kb + (size_t)krow * DK + 32 + quad * 8);
      f32x4 s = (f32x4){0.f, 0.f, 0.f, 0.f};
      s = __builtin_amdgcn_mfma_f32_16x16x32_f16(qf0, kf0, s, 0, 0, 0);
      s = __builtin_amdgcn_mfma_f32_16x16x32_f16(qf1, kf1, s, 0, 0, 0);
#pragma unroll
      for (int r = 0; r < 4; r++) {
        int qr = qrb + quad * 4 + r;
        s[r] += slab[(k0 + kt * 16 + l15) + 63 - qr];
      }
      st[kt] = s;
    }

    // online softmax
    float cm[4];
#pragma unroll
    for (int r = 0; r < 4; r++)
      cm[r] = fmaxf(fmaxf(st[0][r], st[1][r]), fmaxf(st[2][r], st[3][r]));
#pragma unroll
    for (int off = 1; off < 16; off <<= 1)
#pragma unroll
      for (int r = 0; r < 4; r++) cm[r] = fmaxf(cm[r], __shfl_xor(cm[r], off, 64));
#pragma unroll
    for (int r = 0; r < 4; r++) {
      float mnew = fmaxf(mrow[r], cm[r]);
      float alpha = __expf(mrow[r] - mnew);
      mrow[r] = mnew;
      lrow[r] *= alpha;
#pragma unroll
      for (int dt = 0; dt < 4; dt++) o[dt][r] *= alpha;
    }
    // P = exp(S - m), stash to LDS in A-layout row-major [q][k]
#pragma unroll
    for (int kt = 0; kt < 4; kt++)
#pragma unroll
      for (int r = 0; r < 4; r++) {
        float p = __expf(st[kt][r] - mrow[r]);
        lrow[r] += p;
        Ps[w][(quad * 4 + r) * 72 + kt * 16 + l15] = (_Float16)p;
      }
    __asm__ volatile("s_waitcnt lgkmcnt(0)" ::: "memory");  // wave-local LDS RAW

    half8 pf0 = *(half8*)&Ps[w][l15 * 72 + quad * 8];
    half8 pf1 = *(half8*)&Ps[w][l15 * 72 + 32 + quad * 8];
#pragma unroll
    for (int dt = 0; dt < 4; dt++) {
      half8 vf0 = *(half8*)&Vt[(dt * 16 + l15) * 72 + quad * 8];
      half8 vf1 = *(half8*)&Vt[(dt * 16 + l15) * 72 + 32 + quad * 8];
      o[dt] = __builtin_amdgcn_mfma_f32_16x16x32_f16(pf0, vf0, o[dt], 0, 0, 0);
      o[dt] = __builtin_amdgcn_mfma_f32_16x16x32_f16(pf1, vf1, o[dt], 0, 0, 0);
    }
  }

  // finalize: reduce l across the 16 columns, normalize, store (b,s,h*64+d) f16
#pragma unroll
  for (int off = 1; off < 16; off <<= 1)
#pragma unroll
    for (int r = 0; r < 4; r++) lrow[r] += __shfl_xor(lrow[r], off, 64);
#pragma unroll
  for (int r = 0; r < 4; r++) lrow[r] = 1.0f / lrow[r];
#pragma unroll
  for (int dt = 0; dt < 4; dt++)
#pragma unroll
    for (int r = 0; r < 4; r++) {
      int s_idx = q0 + qrb + quad * 4 + r;
      attn_out[((size_t)(b * S_LEN + s_idx)) * DM + h * DK + dt * 16 + l15] =
          (_Float16)(o[dt][r] * lrow[r]);
    }
}

// ---------------- launch ----------------
extern "C" void kernel_launch(void* const* d_in, const int* in_sizes, int n_in,
                              void* d_out, int out_size, void* d_ws, size_t ws_size,
                              hipStream_t stream) {
  const float* hs  = (const float*)d_in[0];
  const float* Wq  = (const float*)d_in[1];
  const float* Wk  = (const float*)d_in[2];
  const float* Wv  = (const float*)d_in[3];
  const float* Wo  = (const float*)d_in[4];
  const float* tbl = (const float*)d_in[5];
  float* out = (float*)d_out;
  char* ws = (char*)d_ws;

  _Float16* Xh    = (_Float16*)(ws);                    // 8 MB
  _Float16* Wqkvt = (_Float16*)(ws + (8u << 20));       // 6 MB (Wq|Wk|Wv transposed)
  _Float16* Wot   = (_Float16*)(ws + (14u << 20));      // 2 MB
  _Float16* Qd    = (_Float16*)(ws + (16u << 20));      // 8 MB each, Q|K|V contiguous
  _Float16* Kd    = (_Float16*)(ws + (24u << 20));
  _Float16* Vd    = (_Float16*)(ws + (32u << 20));
  _Float16* Ah    = (_Float16*)(ws + (40u << 20));      // 8 MB attention out (b,s,h*d)
  float*    btab  = (float*)(ws + (48u << 20));         // 16*4095 f32

  conv_f32_f16<<<4096, 256, 0, stream>>>(hs, Xh, (NB * S_LEN * DM) / 4);
  dim3 tb(32, 8), tg(32, 32);
  transpose_conv<<<tg, tb, 0, stream>>>(Wq, Wqkvt);
  transpose_conv<<<tg, tb, 0, stream>>>(Wk, Wqkvt + 1048576);
  transpose_conv<<<tg, tb, 0, stream>>>(Wv, Wqkvt + 2097152);
  transpose_conv<<<tg, tb, 0, stream>>>(Wo, Wot);
  bias_tab_kernel<<<256, 256, 0, stream>>>(tbl, btab);

  gemm_f16<0><<<dim3(24, 32), 256, 0, stream>>>(Xh, Wqkvt, (void*)Qd, NB * S_LEN, 3 * DM, DM);
  attn_kernel<<<dim3(S_LEN / 64, NH, NB), 256, 0, stream>>>(Qd, Kd, Vd, btab, Ah);
  gemm_f16<1><<<dim3(8, 32), 256, 0, stream>>>(Ah, Wot, (void*)out, NB * S_LEN, DM, DM);
}

// Round 3
// 221.673 us; speedup vs baseline: 1.3785x; 1.3785x over previous
//
#include <hip/hip_runtime.h>
#include <hip/hip_fp16.h>

#define S_LEN 2048
#define NH 16
#define DK 64
#define DM 1024
#define NB 2
#define QKV_SZ (NB * NH * S_LEN * DK)  // 4194304 halfs per tensor

typedef _Float16 half8 __attribute__((ext_vector_type(8)));
typedef _Float16 half4v __attribute__((ext_vector_type(4)));
typedef __fp16 fp16x2 __attribute__((ext_vector_type(2)));
typedef float f32x4 __attribute__((ext_vector_type(4)));

// pack 4 f32 -> 4 f16 (rtz) as one 64-bit value
static __device__ __forceinline__ half4v pack4(const f32x4 v) {
  fp16x2 lo = __builtin_amdgcn_cvt_pkrtz(v[0], v[1]);
  fp16x2 hi = __builtin_amdgcn_cvt_pkrtz(v[2], v[3]);
  half4v r;
  ((fp16x2*)&r)[0] = lo;
  ((fp16x2*)&r)[1] = hi;
  return r;
}

#define GLL(gp, lp)                                                              \
  __builtin_amdgcn_global_load_lds(                                              \
      (const __attribute__((address_space(1))) unsigned int*)(gp),               \
      (__attribute__((address_space(3))) unsigned int*)(lp), 16, 0, 0)

// ---------------- conversion kernels ----------------

__global__ __launch_bounds__(256) void conv_f32_f16(const float* __restrict__ in,
                                                    _Float16* __restrict__ out, int n4) {
  int i = blockIdx.x * 256 + threadIdx.x;
  if (i >= n4) return;
  float4 v = ((const float4*)in)[i];
  half4v o;
  o[0] = (_Float16)v.x; o[1] = (_Float16)v.y; o[2] = (_Float16)v.z; o[3] = (_Float16)v.w;
  ((half4v*)out)[i] = o;
}

// Wt[n][k] = (f16)(scale * W[k][n]), both 1024x1024
__global__ __launch_bounds__(256) void transpose_conv(const float* __restrict__ W,
                                                      _Float16* __restrict__ Wt, float scale) {
  __shared__ float tile[32][33];
  int tx = threadIdx.x, ty = threadIdx.y;
  int nx = blockIdx.x * 32 + tx;
  int ky = blockIdx.y * 32;
#pragma unroll
  for (int i = 0; i < 32; i += 8) tile[ty + i][tx] = W[(size_t)(ky + ty + i) * DM + nx];
  __syncthreads();
  int kx = ky + tx;
  int ny = blockIdx.x * 32;
#pragma unroll
  for (int i = 0; i < 32; i += 8)
    Wt[(size_t)(ny + ty + i) * DM + kx] = (_Float16)(tile[tx][ty + i] * scale);
}

// tab[h][r] = log2(e) * table[bucket(r-2047)][h], r in [0,4095)
__global__ __launch_bounds__(256) void bias_tab_kernel(const float* __restrict__ table,
                                                       float* __restrict__ tab) {
  int i = blockIdx.x * 256 + threadIdx.x;
  if (i >= NH * 4095) return;
  int h = i / 4095, r = i - h * 4095;
  int rel = r - 2047;              // rel = k - q
  int bucket = rel > 0 ? 16 : 0;
  int a = rel < 0 ? -rel : rel;
  if (a < 8) {
    bucket += a;
  } else {
    int lg = 31 - __clz(a * a);    // floor(2*log2(a))
    int large = 8 + (lg - 6);
    bucket += (large < 15 ? large : 15);
  }
  tab[i] = table[bucket * NH + h] * 1.44269504f;
}

// ---------------- fp16 MFMA GEMM: C = A(MxK) @ Bt(NxK)^T ----------------
// MODE 0: scatter f16 into Q[b,h,s,d] | K[b,h,s,d] | V^T[b,h,d,s]; MODE 1: f32 row-major.
template <int MODE>
__global__ __launch_bounds__(256) void gemm_f16(const _Float16* __restrict__ A,
                                                const _Float16* __restrict__ Bt,
                                                void* __restrict__ Cout,
                                                int M, int N, int K) {
  __shared__ _Float16 As[128 * 32];  // swizzled (no pad; global_load_lds)
  __shared__ _Float16 Bs[128 * 32];
  const int t = threadIdx.x;
  const int m0 = blockIdx.y * 128, n0 = blockIdx.x * 128;
  const int w = t >> 6, lane = t & 63, l15 = lane & 15, quad = lane >> 4;
  const int wr = (w >> 1) * 64, wc = (w & 1) * 64;
  const int swz = (quad ^ (l15 & 3)) * 8;

  f32x4 acc[4][4];
#pragma unroll
  for (int i = 0; i < 4; i++)
#pragma unroll
    for (int j = 0; j < 4; j++) acc[i][j] = (f32x4){0.f, 0.f, 0.f, 0.f};

  for (int k0 = 0; k0 < K; k0 += 32) {
    __syncthreads();
#pragma unroll
    for (int i = 0; i < 2; i++) {
      int id = t + 256 * i;
      int row = id >> 2, c = id & 3;
      int cg = c ^ (row & 3);
      GLL(A + (size_t)(m0 + row) * K + k0 + cg * 8, (char*)As + id * 16);
      GLL(Bt + (size_t)(n0 + row) * K + k0 + cg * 8, (char*)Bs + id * 16);
    }
    __syncthreads();
    half8 af[4], bf[4];
#pragma unroll
    for (int i = 0; i < 4; i++) af[i] = *(const half8*)(As + (wr + i * 16 + l15) * 32 + swz);
#pragma unroll
    for (int i = 0; i < 4; i++) bf[i] = *(const half8*)(Bs + (wc + i * 16 + l15) * 32 + swz);
#pragma unroll
    for (int i = 0; i < 4; i++)
#pragma unroll
      for (int j = 0; j < 4; j++)
        acc[i][j] = __builtin_amdgcn_mfma_f32_16x16x32_f16(af[i], bf[j], acc[i][j], 0, 0, 0);
  }

#pragma unroll
  for (int i = 0; i < 4; i++)
#pragma unroll
    for (int j = 0; j < 4; j++) {
      int row0 = m0 + wr + i * 16 + quad * 4;   // C/D: row=(lane>>4)*4+reg
      int col = n0 + wc + j * 16 + l15;         //      col=lane&15
      if (MODE == 1) {
#pragma unroll
        for (int r = 0; r < 4; r++)
          ((float*)Cout)[(size_t)(row0 + r) * N + col] = acc[i][j][r];
      } else {
        int which = col >> 10, rem = col & 1023, hh = rem >> 6, dd = rem & 63;
        int bb = row0 >> 11, ss = row0 & 2047;
        _Float16* base = (_Float16*)Cout;
        if (which == 2) {  // V: transposed store [b,h,d,s], 4 consecutive s -> b64
          *(half4v*)(base + (size_t)2 * QKV_SZ +
                     ((size_t)((bb * NH + hh) * DK + dd)) * S_LEN + ss) = pack4(acc[i][j]);
        } else {
#pragma unroll
          for (int r = 0; r < 4; r++)
            base[(size_t)which * QKV_SZ +
                 ((size_t)((bb * NH + hh) * S_LEN) + ss + r) * DK + dd] = (_Float16)acc[i][j][r];
        }
      }
    }
}

// ---------------- flash attention (S^T formulation) ----------------
// grid (S/128, H, B), block 256 = 4 waves; wave w owns q in [Q0+32w, Q0+32w+32)
// Computes S^T = K Q^T (+bias), online softmax per-lane (q=lane&15), O^T = V^T P^T.
__global__ __launch_bounds__(256, 2) void attn_kernel(
    const _Float16* __restrict__ Q, const _Float16* __restrict__ K,
    const _Float16* __restrict__ Vt, const float* __restrict__ btab,
    _Float16* __restrict__ attn_out) {
  __shared__ _Float16 Ks[2][4096];   // [key][d] swizzled, 64x64, dbuf
  __shared__ _Float16 Vs[2][4096];   // [d][key] swizzled, 64x64, dbuf
  __shared__ _Float16 Ps[4][32 * 72];// per-wave P [q][key], pad 64->72
  __shared__ float slab[640];        // bias, rel = i-317, log2e-scaled

  const int t = threadIdx.x;
  const int Q0 = blockIdx.x * 128;
  const int h = blockIdx.y, b = blockIdx.z;
  const int w = t >> 6, lane = t & 63, l15 = lane & 15, quad = lane >> 4;
  const int qw0 = Q0 + w * 32;

  const _Float16* Qb = Q + (size_t)(b * NH + h) * S_LEN * DK;
  const _Float16* Kb = K + (size_t)(b * NH + h) * S_LEN * DK;
  const _Float16* Vb = Vt + (size_t)(b * NH + h) * S_LEN * DK;  // [d][s]

  for (int i = t; i < 635; i += 256) slab[i] = btab[h * 4095 + 1730 + i];

  // Q B-fragments (B[k=d][n=q]): qf[qt][dh]
  half8 qf[2][2];
#pragma unroll
  for (int qt = 0; qt < 2; qt++)
#pragma unroll
    for (int dh = 0; dh < 2; dh++)
      qf[qt][dh] = *(const half8*)(Qb + (size_t)(qw0 + qt * 16 + l15) * DK + dh * 32 + quad * 8);

  f32x4 o[2][4];
#pragma unroll
  for (int qt = 0; qt < 2; qt++)
#pragma unroll
    for (int dt = 0; dt < 4; dt++) o[qt][dt] = (f32x4){0.f, 0.f, 0.f, 0.f};
  float m_[2] = {-INFINITY, -INFINITY};
  float l_[2] = {0.f, 0.f};

  auto stage = [&](int kc, int bi) {
#pragma unroll
    for (int i = 0; i < 2; i++) {
      int id = t + 256 * i;
      int row = id >> 3, c = id & 7;
      int cg = c ^ (row & 7);
      GLL(Kb + (size_t)(kc + row) * DK + cg * 8, (char*)(&Ks[bi][0]) + id * 16);
      GLL(Vb + (size_t)row * S_LEN + kc + cg * 8, (char*)(&Vs[bi][0]) + id * 16);
    }
  };

  stage(0, 0);
  __syncthreads();

  for (int k0 = 0; k0 < S_LEN; k0 += 64) {
    const int bi = (k0 >> 6) & 1;
    if (k0 + 64 < S_LEN) stage(k0 + 64, bi ^ 1);  // prefetch into other buffer

    const int dk0 = k0 - qw0;
    const bool farneg = (dk0 <= -191);   // all rel <= -128: bias const
    const bool farpos = (dk0 >= 159);    // all rel >= +128: bias const
    const bool nearc = !(farneg || farpos);
    const float cb = farneg ? slab[189] : slab[445];

    // S^T accumulators; init with bias (near) or zero (far; bias folded into m)
    f32x4 st[2][4];
    if (nearc) {
#pragma unroll
      for (int qt = 0; qt < 2; qt++)
#pragma unroll
        for (int kt = 0; kt < 4; kt++) {
          int i0 = dk0 + kt * 16 + quad * 4 - qt * 16 - l15 + 317;
          f32x4 v;
          v[0] = slab[i0]; v[1] = slab[i0 + 1]; v[2] = slab[i0 + 2]; v[3] = slab[i0 + 3];
          st[qt][kt] = v;
        }
    } else {
#pragma unroll
      for (int qt = 0; qt < 2; qt++)
#pragma unroll
        for (int kt = 0; kt < 4; kt++) st[qt][kt] = (f32x4){0.f, 0.f, 0.f, 0.f};
    }

    // K A-fragments (A[m=key][k=d]) from swizzled LDS
    half8 kf[4][2];
#pragma unroll
    for (int kt = 0; kt < 4; kt++)
#pragma unroll
      for (int dh = 0; dh < 2; dh++)
        kf[kt][dh] = *(const half8*)(&Ks[bi][(kt * 16 + l15) * 64 +
                                             (((dh << 2) + quad) ^ (l15 & 7)) * 8]);
#pragma unroll
    for (int qt = 0; qt < 2; qt++)
#pragma unroll
      for (int kt = 0; kt < 4; kt++)
#pragma unroll
        for (int dh = 0; dh < 2; dh++)
          st[qt][kt] = __builtin_amdgcn_mfma_f32_16x16x32_f16(kf[kt][dh], qf[qt][dh],
                                                              st[qt][kt], 0, 0, 0);

    // online softmax; state per lane (q = qt*16 + l15)
#pragma unroll
    for (int qt = 0; qt < 2; qt++) {
      float cm = fmaxf(fmaxf(st[qt][0][0], st[qt][0][1]), fmaxf(st[qt][0][2], st[qt][0][3]));
#pragma unroll
      for (int kt = 1; kt < 4; kt++)
        cm = fmaxf(cm, fmaxf(fmaxf(st[qt][kt][0], st[qt][kt][1]),
                             fmaxf(st[qt][kt][2], st[qt][kt][3])));
      cm = fmaxf(cm, __shfl_xor(cm, 16));
      cm = fmaxf(cm, __shfl_xor(cm, 32));
      float mc = nearc ? cm : cm + cb;
      float mnew = fmaxf(m_[qt], mc);
      float alpha = __builtin_amdgcn_exp2f(m_[qt] - mnew);
      m_[qt] = mnew;
      float msub = nearc ? mnew : mnew - cb;
      l_[qt] *= alpha;
#pragma unroll
      for (int dt = 0; dt < 4; dt++) o[qt][dt] *= alpha;
#pragma unroll
      for (int kt = 0; kt < 4; kt++) {
        f32x4 p;
#pragma unroll
        for (int r = 0; r < 4; r++) p[r] = __builtin_amdgcn_exp2f(st[qt][kt][r] - msub);
        l_[qt] += (p[0] + p[1]) + (p[2] + p[3]);
        // 4 consecutive keys per lane -> single b64 write
        *(half4v*)(&Ps[w][(qt * 16 + l15) * 72 + kt * 16 + quad * 4]) = pack4(p);
      }
    }
    __asm__ volatile("s_waitcnt lgkmcnt(0)" ::: "memory");  // wave-local P RAW

    // O^T += V^T P^T : A = V^T frag, B = P^T frag (reads P[q][key] rows)
    half8 pf[2][2], vf[4][2];
#pragma unroll
    for (int qt = 0; qt < 2; qt++)
#pragma unroll
      for (int kh = 0; kh < 2; kh++)
        pf[qt][kh] = *(const half8*)(&Ps[w][(qt * 16 + l15) * 72 + kh * 32 + quad * 8]);
#pragma unroll
    for (int dt = 0; dt < 4; dt++)
#pragma unroll
      for (int kh = 0; kh < 2; kh++)
        vf[dt][kh] = *(const half8*)(&Vs[bi][(dt * 16 + l15) * 64 +
                                             (((kh << 2) + quad) ^ (l15 & 7)) * 8]);
#pragma unroll
    for (int qt = 0; qt < 2; qt++)
#pragma unroll
      for (int dt = 0; dt < 4; dt++)
#pragma unroll
        for (int kh = 0; kh < 2; kh++)
          o[qt][dt] = __builtin_amdgcn_mfma_f32_16x16x32_f16(vf[dt][kh], pf[qt][kh],
                                                             o[qt][dt], 0, 0, 0);
    __syncthreads();  // buf bi free for next-next prefetch; drains this prefetch
  }

  // finalize: reduce l over quads, normalize, store O^T (4 consecutive d -> b64)
#pragma unroll
  for (int qt = 0; qt < 2; qt++) {
    float lf = l_[qt];
    lf += __shfl_xor(lf, 16);
    lf += __shfl_xor(lf, 32);
    float inv = 1.0f / lf;
    int q = qw0 + qt * 16 + l15;
#pragma unroll
    for (int dt = 0; dt < 4; dt++) {
      f32x4 ov = o[qt][dt] * inv;
      *(half4v*)(attn_out + ((size_t)(b * S_LEN + q)) * DM + h * DK + dt * 16 + quad * 4) =
          pack4(ov);
    }
  }
}

// ---------------- launch ----------------
extern "C" void kernel_launch(void* const* d_in, const int* in_sizes, int n_in,
                              void* d_out, int out_size, void* d_ws, size_t ws_size,
                              hipStream_t stream) {
  const float* hs  = (const float*)d_in[0];
  const float* Wq  = (const float*)d_in[1];
  const float* Wk  = (const float*)d_in[2];
  const float* Wv  = (const float*)d_in[3];
  const float* Wo  = (const float*)d_in[4];
  const float* tbl = (const float*)d_in[5];
  float* out = (float*)d_out;
  char* ws = (char*)d_ws;

  _Float16* Xh    = (_Float16*)(ws);                    // 8 MB
  _Float16* Wqkvt = (_Float16*)(ws + (8u << 20));       // 6 MB (Wq|Wk|Wv transposed)
  _Float16* Wot   = (_Float16*)(ws + (14u << 20));      // 2 MB
  _Float16* Qd    = (_Float16*)(ws + (16u << 20));      // Q | K | V^T, 8 MB each
  _Float16* Kd    = Qd + (size_t)QKV_SZ;
  _Float16* Vd    = Qd + (size_t)2 * QKV_SZ;
  _Float16* Ah    = (_Float16*)(ws + (40u << 20));      // 8 MB attention out (b,s,h*d)
  float*    btab  = (float*)(ws + (48u << 20));         // 16*4095 f32

  conv_f32_f16<<<4096, 256, 0, stream>>>(hs, Xh, (NB * S_LEN * DM) / 4);
  dim3 tb(32, 8), tg(32, 32);
  transpose_conv<<<tg, tb, 0, stream>>>(Wq, Wqkvt, 1.44269504f);  // fold log2(e) into Q
  transpose_conv<<<tg, tb, 0, stream>>>(Wk, Wqkvt + 1048576, 1.0f);
  transpose_conv<<<tg, tb, 0, stream>>>(Wv, Wqkvt + 2097152, 1.0f);
  transpose_conv<<<tg, tb, 0, stream>>>(Wo, Wot, 1.0f);
  bias_tab_kernel<<<256, 256, 0, stream>>>(tbl, btab);

  gemm_f16<0><<<dim3(24, 32), 256, 0, stream>>>(Xh, Wqkvt, (void*)Qd, NB * S_LEN, 3 * DM, DM);
  attn_kernel<<<dim3(S_LEN / 128, NH, NB), 256, 0, stream>>>(Qd, Kd, Vd, btab, Ah);
  gemm_f16<1><<<dim3(8, 32), 256, 0, stream>>>(Ah, Wot, (void*)out, NB * S_LEN, DM, DM);
}

// Round 4
// 216.786 us; speedup vs baseline: 1.4095x; 1.0225x over previous
//
#include <hip/hip_runtime.h>
#include <hip/hip_fp16.h>

#define S_LEN 2048
#define NH 16
#define DK 64
#define DM 1024
#define NB 2
#define QKV_SZ (NB * NH * S_LEN * DK)  // 4194304 halfs per tensor

typedef _Float16 half8 __attribute__((ext_vector_type(8)));
typedef _Float16 half4v __attribute__((ext_vector_type(4)));
typedef __fp16 fp16x2 __attribute__((ext_vector_type(2)));
typedef float f32x4 __attribute__((ext_vector_type(4)));

// pack 4 f32 -> 4 f16 (rtz) as one 64-bit value
static __device__ __forceinline__ half4v pack4(const f32x4 v) {
  fp16x2 lo = __builtin_amdgcn_cvt_pkrtz(v[0], v[1]);
  fp16x2 hi = __builtin_amdgcn_cvt_pkrtz(v[2], v[3]);
  half4v r;
  ((fp16x2*)&r)[0] = lo;
  ((fp16x2*)&r)[1] = hi;
  return r;
}

#define GLL(gp, lp)                                                              \
  __builtin_amdgcn_global_load_lds(                                              \
      (const __attribute__((address_space(1))) unsigned int*)(gp),               \
      (__attribute__((address_space(3))) unsigned int*)(lp), 16, 0, 0)

// ---------------- conversion kernels ----------------

__global__ __launch_bounds__(256) void conv_f32_f16(const float* __restrict__ in,
                                                    _Float16* __restrict__ out, int n4) {
  int i = blockIdx.x * 256 + threadIdx.x;
  if (i >= n4) return;
  float4 v = ((const float4*)in)[i];
  half4v o;
  o[0] = (_Float16)v.x; o[1] = (_Float16)v.y; o[2] = (_Float16)v.z; o[3] = (_Float16)v.w;
  ((half4v*)out)[i] = o;
}

// All 4 weight transposes in one launch; z selects matrix.
// Wt[n][k] = (f16)(scale * W[k][n]), 1024x1024 each.
__global__ __launch_bounds__(256) void transpose_conv4(
    const float* __restrict__ Wq, const float* __restrict__ Wk,
    const float* __restrict__ Wv, const float* __restrict__ Wo,
    _Float16* __restrict__ Wqkvt, _Float16* __restrict__ Wot) {
  __shared__ float tile[32][33];
  int z = blockIdx.z;
  const float* W = (z == 0) ? Wq : (z == 1) ? Wk : (z == 2) ? Wv : Wo;
  _Float16* Wt = (z < 3) ? (Wqkvt + (size_t)z * 1048576) : Wot;
  float scale = (z == 0) ? 1.44269504f : 1.0f;  // fold log2(e) into Q path
  int tx = threadIdx.x, ty = threadIdx.y;
  int nx = blockIdx.x * 32 + tx;
  int ky = blockIdx.y * 32;
#pragma unroll
  for (int i = 0; i < 32; i += 8) tile[ty + i][tx] = W[(size_t)(ky + ty + i) * DM + nx];
  __syncthreads();
  int kx = ky + tx;
  int ny = blockIdx.x * 32;
#pragma unroll
  for (int i = 0; i < 32; i += 8)
    Wt[(size_t)(ny + ty + i) * DM + kx] = (_Float16)(tile[tx][ty + i] * scale);
}

// tab[h][r] = log2(e) * table[bucket(r-2047)][h], r in [0,4095)
__global__ __launch_bounds__(256) void bias_tab_kernel(const float* __restrict__ table,
                                                       float* __restrict__ tab) {
  int i = blockIdx.x * 256 + threadIdx.x;
  if (i >= NH * 4095) return;
  int h = i / 4095, r = i - h * 4095;
  int rel = r - 2047;              // rel = k - q
  int bucket = rel > 0 ? 16 : 0;
  int a = rel < 0 ? -rel : rel;
  if (a < 8) {
    bucket += a;
  } else {
    int lg = 31 - __clz(a * a);    // floor(2*log2(a))
    int large = 8 + (lg - 6);
    bucket += (large < 15 ? large : 15);
  }
  tab[i] = table[bucket * NH + h] * 1.44269504f;
}

// ---------------- fp16 MFMA GEMM: C = A(MxK) @ Bt(NxK)^T ----------------
// MODE 0: scatter f16 into Q[b,h,s,d] | K[b,h,s,d] | V^T[b,h,d,s]; MODE 1: f32 row-major.
template <int MODE>
__global__ __launch_bounds__(256) void gemm_f16(const _Float16* __restrict__ A,
                                                const _Float16* __restrict__ Bt,
                                                void* __restrict__ Cout,
                                                int M, int N, int K) {
  __shared__ _Float16 As[128 * 32];  // swizzled (no pad; global_load_lds)
  __shared__ _Float16 Bs[128 * 32];
  const int t = threadIdx.x;
  const int m0 = blockIdx.y * 128, n0 = blockIdx.x * 128;
  const int w = t >> 6, lane = t & 63, l15 = lane & 15, quad = lane >> 4;
  const int wr = (w >> 1) * 64, wc = (w & 1) * 64;
  const int swz = (quad ^ (l15 & 3)) * 8;

  f32x4 acc[4][4];
#pragma unroll
  for (int i = 0; i < 4; i++)
#pragma unroll
    for (int j = 0; j < 4; j++) acc[i][j] = (f32x4){0.f, 0.f, 0.f, 0.f};

  for (int k0 = 0; k0 < K; k0 += 32) {
    __syncthreads();
#pragma unroll
    for (int i = 0; i < 2; i++) {
      int id = t + 256 * i;
      int row = id >> 2, c = id & 3;
      int cg = c ^ (row & 3);
      GLL(A + (size_t)(m0 + row) * K + k0 + cg * 8, (char*)As + id * 16);
      GLL(Bt + (size_t)(n0 + row) * K + k0 + cg * 8, (char*)Bs + id * 16);
    }
    __syncthreads();
    half8 af[4], bf[4];
#pragma unroll
    for (int i = 0; i < 4; i++) af[i] = *(const half8*)(As + (wr + i * 16 + l15) * 32 + swz);
#pragma unroll
    for (int i = 0; i < 4; i++) bf[i] = *(const half8*)(Bs + (wc + i * 16 + l15) * 32 + swz);
#pragma unroll
    for (int i = 0; i < 4; i++)
#pragma unroll
      for (int j = 0; j < 4; j++)
        acc[i][j] = __builtin_amdgcn_mfma_f32_16x16x32_f16(af[i], bf[j], acc[i][j], 0, 0, 0);
  }

#pragma unroll
  for (int i = 0; i < 4; i++)
#pragma unroll
    for (int j = 0; j < 4; j++) {
      int row0 = m0 + wr + i * 16 + quad * 4;   // C/D: row=(lane>>4)*4+reg
      int col = n0 + wc + j * 16 + l15;         //      col=lane&15
      if (MODE == 1) {
#pragma unroll
        for (int r = 0; r < 4; r++)
          ((float*)Cout)[(size_t)(row0 + r) * N + col] = acc[i][j][r];
      } else {
        int which = col >> 10, rem = col & 1023, hh = rem >> 6, dd = rem & 63;
        int bb = row0 >> 11, ss = row0 & 2047;
        _Float16* base = (_Float16*)Cout;
        if (which == 2) {  // V: transposed store [b,h,d,s], 4 consecutive s -> b64
          *(half4v*)(base + (size_t)2 * QKV_SZ +
                     ((size_t)((bb * NH + hh) * DK + dd)) * S_LEN + ss) = pack4(acc[i][j]);
        } else {
#pragma unroll
          for (int r = 0; r < 4; r++)
            base[(size_t)which * QKV_SZ +
                 ((size_t)((bb * NH + hh) * S_LEN) + ss + r) * DK + dd] = (_Float16)acc[i][j][r];
        }
      }
    }
}

// ---------------- flash attention (S^T formulation, high-TLP) ----------------
// grid (S/64, H, B) = 1024 blocks, block 256 = 4 waves; wave w owns q in [Q0+16w, +16)
// S^T = K Q^T (+bias), per-lane online softmax (q=lane&15), O^T = V^T P^T.
__global__ __launch_bounds__(256, 4) void attn_kernel(
    const _Float16* __restrict__ Q, const _Float16* __restrict__ K,
    const _Float16* __restrict__ Vt, const float* __restrict__ btab,
    _Float16* __restrict__ attn_out) {
  __shared__ _Float16 Ks[4096];      // [key][d] 64x64, 16B-XOR swizzled
  __shared__ _Float16 Vs[4096];      // [d][key] 64x64, 16B-XOR swizzled
  __shared__ _Float16 Ps[4][1024];   // per-wave P [q(16)][key(64)], 16B-XOR swizzled
  __shared__ float slab[512];        // bias for rel in [-256,256), log2e-scaled

  const int t = threadIdx.x;
  const int Q0 = blockIdx.x * 64;
  const int h = blockIdx.y, b = blockIdx.z;
  const int w = t >> 6, lane = t & 63, l15 = lane & 15, quad = lane >> 4;
  const int qw0 = Q0 + w * 16;
  const int sw7 = l15 & 7;

  const _Float16* Qb = Q + (size_t)(b * NH + h) * S_LEN * DK;
  const _Float16* Kb = K + (size_t)(b * NH + h) * S_LEN * DK;
  const _Float16* Vb = Vt + (size_t)(b * NH + h) * S_LEN * DK;  // [d][s]

  // slab[i] = bias(rel = i-256): global r = rel+2047 -> btab offset 1791+i
  for (int i = t; i < 512; i += 256) slab[i] = btab[h * 4095 + 1791 + i];

  // Q B-fragments (B[k=d][n=q]): lane(n=l15,quad) holds d = dh*32+quad*8+j
  half8 qf[2];
#pragma unroll
  for (int dh = 0; dh < 2; dh++)
    qf[dh] = *(const half8*)(Qb + (size_t)(qw0 + l15) * DK + dh * 32 + quad * 8);

  f32x4 o[4];
#pragma unroll
  for (int dt = 0; dt < 4; dt++) o[dt] = (f32x4){0.f, 0.f, 0.f, 0.f};
  float m_ = -INFINITY, l_ = 0.f;

  for (int k0 = 0; k0 < S_LEN; k0 += 64) {
    // stage K/V chunk (single-buffered, m97-style)
#pragma unroll
    for (int i = 0; i < 2; i++) {
      int id = t + 256 * i;
      int row = id >> 3, c = id & 7;
      int cg = c ^ (row & 7);
      GLL(Kb + (size_t)(k0 + row) * DK + cg * 8, (char*)Ks + id * 16);
      GLL(Vb + (size_t)row * S_LEN + k0 + cg * 8, (char*)Vs + id * 16);
    }
    __syncthreads();  // drains GLL vmcnt + slab on first iter

    const int dk0 = k0 - qw0;
    const bool farneg = (dk0 <= -191);   // all rel <= -128
    const bool farpos = (dk0 >= 143);    // all rel >= +128
    const bool nearc = !(farneg || farpos);
    const float cb = farneg ? slab[128] : slab[384];

    // S^T accumulators: init with bias (near) or zero (far; const bias via m-shift)
    f32x4 st[4];
    if (nearc) {
#pragma unroll
      for (int kt = 0; kt < 4; kt++) {
        int i0 = dk0 + kt * 16 + quad * 4 - l15 + 256;
        f32x4 v;
        v[0] = slab[i0]; v[1] = slab[i0 + 1]; v[2] = slab[i0 + 2]; v[3] = slab[i0 + 3];
        st[kt] = v;
      }
    } else {
#pragma unroll
      for (int kt = 0; kt < 4; kt++) st[kt] = (f32x4){0.f, 0.f, 0.f, 0.f};
    }

    // K A-fragments + V fragments (issue V early to overlap softmax)
    half8 kf[4][2], vf[4][2];
#pragma unroll
    for (int kt = 0; kt < 4; kt++)
#pragma unroll
      for (int dh = 0; dh < 2; dh++)
        kf[kt][dh] = *(const half8*)(&Ks[(kt * 16 + l15) * 64 + (((dh << 2) + quad) ^ sw7) * 8]);
#pragma unroll
    for (int dt = 0; dt < 4; dt++)
#pragma unroll
      for (int kh = 0; kh < 2; kh++)
        vf[dt][kh] = *(const half8*)(&Vs[(dt * 16 + l15) * 64 + (((kh << 2) + quad) ^ sw7) * 8]);

#pragma unroll
    for (int kt = 0; kt < 4; kt++)
#pragma unroll
      for (int dh = 0; dh < 2; dh++)
        st[kt] = __builtin_amdgcn_mfma_f32_16x16x32_f16(kf[kt][dh], qf[dh], st[kt], 0, 0, 0);

    // online softmax (per-lane state, q = l15; quads hold disjoint keys)
    float cm = fmaxf(fmaxf(st[0][0], st[0][1]), fmaxf(st[0][2], st[0][3]));
#pragma unroll
    for (int kt = 1; kt < 4; kt++)
      cm = fmaxf(cm, fmaxf(fmaxf(st[kt][0], st[kt][1]), fmaxf(st[kt][2], st[kt][3])));
    cm = fmaxf(cm, __shfl_xor(cm, 16));
    cm = fmaxf(cm, __shfl_xor(cm, 32));
    float mc = nearc ? cm : cm + cb;
    if (__any(mc > m_)) {      // wave-uniform skip when running max unchanged
      float mnew = fmaxf(m_, mc);
      float alpha = __builtin_amdgcn_exp2f(m_ - mnew);
      m_ = mnew;
      l_ *= alpha;
#pragma unroll
      for (int dt = 0; dt < 4; dt++) o[dt] *= alpha;
    }
    float msub = nearc ? m_ : m_ - cb;

    f32x4 lacc = (f32x4){0.f, 0.f, 0.f, 0.f};
#pragma unroll
    for (int kt = 0; kt < 4; kt++) {
      f32x4 p;
#pragma unroll
      for (int r = 0; r < 4; r++) p[r] = __builtin_amdgcn_exp2f(st[kt][r] - msub);
      lacc += p;
      // P[q=l15][key=kt*16+quad*4 ..+4] -> b64, group16 swizzle g^=(l15&7)
      int g = 2 * kt + (quad >> 1);
      *(half4v*)(&Ps[w][l15 * 64 + (g ^ sw7) * 8 + (quad & 1) * 4]) = pack4(p);
    }
    l_ += (lacc[0] + lacc[1]) + (lacc[2] + lacc[3]);
    __asm__ volatile("s_waitcnt lgkmcnt(0)" ::: "memory");  // wave-local P RAW

    // O^T += V^T P^T : B-frag of P^T reads P[q][key] rows with swizzle
    half8 pf[2];
#pragma unroll
    for (int kh = 0; kh < 2; kh++)
      pf[kh] = *(const half8*)(&Ps[w][l15 * 64 + (((kh << 2) + quad) ^ sw7) * 8]);
#pragma unroll
    for (int dt = 0; dt < 4; dt++)
#pragma unroll
      for (int kh = 0; kh < 2; kh++)
        o[dt] = __builtin_amdgcn_mfma_f32_16x16x32_f16(vf[dt][kh], pf[kh], o[dt], 0, 0, 0);
    __syncthreads();  // Ks/Vs free for restage
  }

  // finalize: reduce l over quads, normalize, store O^T (4 consecutive d -> b64)
  float lf = l_;
  lf += __shfl_xor(lf, 16);
  lf += __shfl_xor(lf, 32);
  float inv = 1.0f / lf;
  int q = qw0 + l15;
#pragma unroll
  for (int dt = 0; dt < 4; dt++) {
    f32x4 ov = o[dt] * inv;
    *(half4v*)(attn_out + ((size_t)(b * S_LEN + q)) * DM + h * DK + dt * 16 + quad * 4) =
        pack4(ov);
  }
}

// ---------------- launch ----------------
extern "C" void kernel_launch(void* const* d_in, const int* in_sizes, int n_in,
                              void* d_out, int out_size, void* d_ws, size_t ws_size,
                              hipStream_t stream) {
  const float* hs  = (const float*)d_in[0];
  const float* Wq  = (const float*)d_in[1];
  const float* Wk  = (const float*)d_in[2];
  const float* Wv  = (const float*)d_in[3];
  const float* Wo  = (const float*)d_in[4];
  const float* tbl = (const float*)d_in[5];
  float* out = (float*)d_out;
  char* ws = (char*)d_ws;

  _Float16* Xh    = (_Float16*)(ws);                    // 8 MB
  _Float16* Wqkvt = (_Float16*)(ws + (8u << 20));       // 6 MB (Wq|Wk|Wv transposed)
  _Float16* Wot   = (_Float16*)(ws + (14u << 20));      // 2 MB
  _Float16* Qd    = (_Float16*)(ws + (16u << 20));      // Q | K | V^T, 8 MB each
  _Float16* Kd    = Qd + (size_t)QKV_SZ;
  _Float16* Vd    = Qd + (size_t)2 * QKV_SZ;
  _Float16* Ah    = (_Float16*)(ws + (40u << 20));      // 8 MB attention out (b,s,h*d)
  float*    btab  = (float*)(ws + (48u << 20));         // 16*4095 f32

  conv_f32_f16<<<4096, 256, 0, stream>>>(hs, Xh, (NB * S_LEN * DM) / 4);
  transpose_conv4<<<dim3(32, 32, 4), dim3(32, 8), 0, stream>>>(Wq, Wk, Wv, Wo, Wqkvt, Wot);
  bias_tab_kernel<<<256, 256, 0, stream>>>(tbl, btab);

  gemm_f16<0><<<dim3(24, 32), 256, 0, stream>>>(Xh, Wqkvt, (void*)Qd, NB * S_LEN, 3 * DM, DM);
  attn_kernel<<<dim3(S_LEN / 64, NH, NB), 256, 0, stream>>>(Qd, Kd, Vd, btab, Ah);
  gemm_f16<1><<<dim3(8, 32), 256, 0, stream>>>(Ah, Wot, (void*)out, NB * S_LEN, DM, DM);
}